// Round 9
// baseline (2296.145 us; speedup 1.0000x reference)
//
#include <hip/hip_runtime.h>

#define T_SEQ 2048
#define NBATCH 64
#define DIM 128      // SEQ_LEN
#define HID 128      // HIDDEN
#define G4 512       // 4*HID
#define NBB 4        // batches per block
#define NBLK (NBATCH / NBB)   // 16 blocks
#define LOG2E 1.44269504088896f

typedef _Float16 h2v   __attribute__((ext_vector_type(2)));
typedef _Float16 f16x8 __attribute__((ext_vector_type(8)));
typedef float    f32x4 __attribute__((ext_vector_type(4)));
typedef float    f32x2 __attribute__((ext_vector_type(2)));

__device__ __forceinline__ float rcp_(float x)  { return __builtin_amdgcn_rcpf(x); }
__device__ __forceinline__ float exp2_(float x) { return __builtin_amdgcn_exp2f(x); }
// sigmoid with input pre-scaled by log2e
__device__ __forceinline__ float sig2_(float a) { return rcp_(1.0f + exp2_(-a)); }
// tanh with input pre-scaled by 2*log2e: tanh(x) = 1 - 2/(1+2^a)
__device__ __forceinline__ float tanh2_(float a) {
    return fmaf(-2.0f, rcp_(1.0f + exp2_(a)), 1.0f);
}
// barrier draining ONLY lgkm (ds) — vm loads keep flowing across it
__device__ __forceinline__ void barrier_lgkm() {
    asm volatile("s_waitcnt lgkmcnt(0)\n\ts_barrier" ::: "memory");
    __builtin_amdgcn_sched_barrier(0);
}

// byte offset into a [16 rows][128 f16] tile, XOR-swizzled (bijective per row)
__device__ __forceinline__ int hswz(int row, int halfidx) {
    int byte = (row << 8) + (halfidx << 1);
    return byte ^ ((row & 15) << 4);
}
// byte offset into gates tile [NBB][128 units][4 f32], XOR-swizzled
__device__ __forceinline__ int gswz(int b, int u) {
    return (b << 11) + ((u ^ (b << 2)) << 4);
}

// ---- prep: x f32 -> f16 (same layout); pack fcw into pairs; scaled bias ----
__global__ __launch_bounds__(256) void prep(
    const float* __restrict__ x,      // [B][T][DIM] f32
    const float* __restrict__ fcw,    // [2][T*HID]
    const float* __restrict__ bias,   // [G4] gate-major
    _Float16* __restrict__ x16,       // [B][T][DIM] f16
    float* __restrict__ fc2,          // [T*HID][2]
    float* __restrict__ bias_s)       // [512] channel = 4*unit+gate, scaled
{
    const size_t gtid   = (size_t)blockIdx.x * blockDim.x + threadIdx.x;
    const size_t stride = (size_t)gridDim.x * blockDim.x;

    const size_t n_x2 = (size_t)NBATCH * T_SEQ * DIM / 2;
    for (size_t i = gtid; i < n_x2; i += stride) {
        float2 v = reinterpret_cast<const float2*>(x)[i];
        h2v p; p.x = (_Float16)v.x; p.y = (_Float16)v.y;
        reinterpret_cast<h2v*>(x16)[i] = p;
    }
    const size_t n_f = (size_t)T_SEQ * HID;
    for (size_t i = gtid; i < n_f; i += stride) {
        fc2[2 * i]     = fcw[i];
        fc2[2 * i + 1] = fcw[n_f + i];
    }
    for (size_t i = gtid; i < 512; i += stride) {
        int gate = (int)i & 3, u = (int)i >> 2;
        float sc = (gate == 2) ? 2.0f * LOG2E : LOG2E;
        bias_s[i] = bias[gate * HID + u] * sc;
    }
}

// ---- fused scan: 16 blocks x 512 threads, 4 batches/block.
// Phase A: D[ch 512][col 16] = bias + Wih~.x_t + Whh~.h_t via mfma_f32_16x16x32_f16
//   (cols 0..3 = real batches, 4..15 fed zeros from padded LDS rows).
//   Lanes col<4 write gates f32x4 to LDS.
// Phase B: thread tid owns (b=tid>>7, u=tid&127): dense 1-unit epilogue,
//   c/f-accums thread-resident; writes h f16 to swizzled tile; stages x_{t+1}.
__global__ __launch_bounds__(512, 1) void lstm_fused(
    const _Float16* __restrict__ x16, // [B][T][DIM] f16
    const float* __restrict__ Wih,    // [DIM][G4]
    const float* __restrict__ Whh,    // [HID][G4]
    const float* __restrict__ h0,
    const float* __restrict__ c0,
    const float* __restrict__ fc2,    // [T*HID][2]
    const float* __restrict__ fcb,
    const float* __restrict__ bias_s, // [512] scaled
    float* __restrict__ out)          // [B][2]
{
    __shared__ _Float16 h_lds[2][16][128];   // 8 KB, rows NBB..15 stay zero
    __shared__ _Float16 x_lds[2][16][128];   // 8 KB, rows NBB..15 stay zero
    __shared__ float    g_lds[NBB][128][4];  // 8 KB gates
    __shared__ float    red[8][2];

    const int tid = threadIdx.x;
    const int w   = tid >> 6;
    const int l   = tid & 63;
    const int col = l & 15;
    const int hi  = l >> 4;
    const int bg  = blockIdx.x;

    // epilogue identity: one (batch, unit) per thread
    const int eb = tid >> 7;          // 0..3 local batch
    const int eu = tid & 127;         // unit
    const int gb = bg * NBB + eb;     // global batch

    // ---- static A fragments for both GEMMs (128 VGPR), log2e-scaled f16
    f16x8 aX[4][4], aH[4][4];
    #pragma unroll
    for (int j = 0; j < 4; ++j) {
        const int chr  = 64 * w + 16 * j + col;          // A-row channel
        const int wcol = (chr & 3) * HID + (chr >> 2);   // weight column
        const float sc = ((chr & 3) == 2) ? 2.0f * LOG2E : LOG2E;
        #pragma unroll
        for (int ks = 0; ks < 4; ++ks) {
            f16x8 ax, ah;
            #pragma unroll
            for (int i = 0; i < 8; ++i) {
                int k = ks * 32 + hi * 8 + i;
                ax[i] = (_Float16)(Wih[(size_t)k * G4 + wcol] * sc);
                ah[i] = (_Float16)(Whh[(size_t)k * G4 + wcol] * sc);
            }
            aX[j][ks] = ax; aH[j][ks] = ah;
        }
    }
    // scaled bias accumulator init (channels 64w+16j+4hi+0..3)
    f32x4 bv[4];
    #pragma unroll
    for (int j = 0; j < 4; ++j)
        bv[j] = *reinterpret_cast<const f32x4*>(bias_s + 64 * w + 16 * j + 4 * hi);

    // ---- zero h/x tiles (padding rows included)
    for (int i = tid; i < 2 * 16 * 128; i += 512) {
        reinterpret_cast<_Float16*>(h_lds)[i] = (_Float16)0.f;
        reinterpret_cast<_Float16*>(x_lds)[i] = (_Float16)0.f;
    }
    float c  = c0[(size_t)gb * HID + eu];
    float hv = h0[(size_t)gb * HID + eu];
    float f0 = 0.f, f1 = 0.f;
    __syncthreads();

    // initial h, x_0 staging, x_1 prefetch
    *reinterpret_cast<_Float16*>(
        reinterpret_cast<char*>(&h_lds[0][0][0]) + hswz(eb, eu)) = (_Float16)hv;
    uint2 xr = {0, 0};
    if (tid < 128) {
        const int xb_ = tid >> 5, seg = tid & 31;
        const _Float16* xs = x16 + ((size_t)(bg * NBB + xb_) * T_SEQ) * DIM + seg * 4;
        uint2 x0 = *reinterpret_cast<const uint2*>(xs);
        *reinterpret_cast<uint2*>(
            reinterpret_cast<char*>(&x_lds[0][0][0]) + hswz(xb_, seg * 4)) = x0;
        xr = *reinterpret_cast<const uint2*>(xs + DIM);   // t = 1
    }
    f32x2 fcp = *reinterpret_cast<const f32x2*>(fc2 + 2 * (size_t)eu);
    f32x2 fcn = *reinterpret_cast<const f32x2*>(fc2 + 2 * ((size_t)HID + eu));
    __syncthreads();

    for (int t = 0; t < T_SEQ; ++t) {
        const int cur = t & 1;
        const char* hb = reinterpret_cast<const char*>(&h_lds[cur][0][0]);
        const char* xb = reinterpret_cast<const char*>(&x_lds[cur][0][0]);

        // ---- Phase A: fragments + 32 MFMA + gates write
        f16x8 fh[4], fx[4];
        #pragma unroll
        for (int ks = 0; ks < 4; ++ks) {
            const int off = hswz(col, ks * 32 + hi * 8);
            fh[ks] = *reinterpret_cast<const f16x8*>(hb + off);
            fx[ks] = *reinterpret_cast<const f16x8*>(xb + off);
        }
        f32x4 acc[4];
        #pragma unroll
        for (int j = 0; j < 4; ++j) {
            f32x4 a = bv[j];
            #pragma unroll
            for (int ks = 0; ks < 4; ++ks)
                a = __builtin_amdgcn_mfma_f32_16x16x32_f16(aX[j][ks], fx[ks], a, 0, 0, 0);
            #pragma unroll
            for (int ks = 0; ks < 4; ++ks)
                a = __builtin_amdgcn_mfma_f32_16x16x32_f16(aH[j][ks], fh[ks], a, 0, 0, 0);
            acc[j] = a;
        }
        if (col < NBB) {
            #pragma unroll
            for (int j = 0; j < 4; ++j) {
                const int u = 16 * w + 4 * j + hi;
                *reinterpret_cast<f32x4*>(
                    reinterpret_cast<char*>(&g_lds[0][0][0]) + gswz(col, u)) = acc[j];
            }
        }
        barrier_lgkm();

        // ---- Phase B: dense epilogue (one unit per thread)
        f32x4 g = *reinterpret_cast<const f32x4*>(
            reinterpret_cast<const char*>(&g_lds[0][0][0]) + gswz(eb, eu));
        float gi = sig2_(g[0]);
        float gf = sig2_(g[1]);
        float gg = tanh2_(g[2]);
        float go = sig2_(g[3]);
        c = fmaf(gf, c, gi * gg);
        float hn = go * tanh2_(2.0f * LOG2E * c);
        f0 = fmaf(hn, fcp.x, f0);
        f1 = fmaf(hn, fcp.y, f1);
        fcp = fcn;
        *reinterpret_cast<_Float16*>(
            reinterpret_cast<char*>(&h_lds[cur ^ 1][0][0]) + hswz(eb, eu)) = (_Float16)hn;
        if (tid < 128) {
            const int xb_ = tid >> 5, seg = tid & 31;
            *reinterpret_cast<uint2*>(
                reinterpret_cast<char*>(&x_lds[cur ^ 1][0][0]) + hswz(xb_, seg * 4)) = xr;
            const int tn = (t + 2 < T_SEQ) ? t + 2 : T_SEQ - 1;
            xr = *reinterpret_cast<const uint2*>(
                x16 + ((size_t)(bg * NBB + xb_) * T_SEQ + tn) * DIM + seg * 4);
        }
        const int tf = (t + 2 < T_SEQ) ? t + 2 : T_SEQ - 1;
        fcn = *reinterpret_cast<const f32x2*>(fc2 + 2 * ((size_t)tf * HID + eu));
        barrier_lgkm();
    }

    // ---- FC head: reduce f0/f1 over units (2 waves per batch)
    float s0 = f0, s1 = f1;
    #pragma unroll
    for (int d = 32; d >= 1; d >>= 1) {
        s0 += __shfl_xor(s0, d);
        s1 += __shfl_xor(s1, d);
    }
    if (l == 0) { red[w][0] = s0; red[w][1] = s1; }
    __syncthreads();
    if (tid < 8) {
        int b = tid >> 1, o = tid & 1;
        out[(bg * NBB + b) * 2 + o] = red[2 * b][o] + red[2 * b + 1][o] + fcb[o];
    }
}

extern "C" void kernel_launch(void* const* d_in, const int* in_sizes, int n_in,
                              void* d_out, int out_size, void* d_ws, size_t ws_size,
                              hipStream_t stream) {
    const float* x    = (const float*)d_in[0];
    const float* h0   = (const float*)d_in[1];
    const float* c0   = (const float*)d_in[2];
    const float* Wih  = (const float*)d_in[3];
    const float* Whh  = (const float*)d_in[4];
    const float* bias = (const float*)d_in[5];
    const float* fcw  = (const float*)d_in[6];
    const float* fcb  = (const float*)d_in[7];
    float* out = (float*)d_out;

    // ws layout: x16 (32 MB) | fc2 (2 MB) | bias_s (2 KB)
    char* wsb = (char*)d_ws;
    _Float16* x16    = (_Float16*)wsb;
    float*    fc2    = (float*)(wsb + (size_t)NBATCH * T_SEQ * DIM * 2);
    float*    bias_s = (float*)(wsb + (size_t)NBATCH * T_SEQ * DIM * 2
                                     + (size_t)T_SEQ * HID * 2 * 4);

    prep<<<512, 256, 0, stream>>>(x, fcw, bias, x16, fc2, bias_s);
    lstm_fused<<<NBLK, 512, 0, stream>>>(x16, Wih, Whh, h0, c0, fc2, fcb, bias_s, out);
}